// Round 10
// baseline (117.055 us; speedup 1.0000x reference)
//
#include <hip/hip_runtime.h>
#include <stdint.h>

// Problem constants (fixed by setup_inputs)
#define NB 32
#define NCH 128
#define NH 56
#define NW 56
#define NHW_ 3136
#define NPIX 100352
#define PADD 58                              // padded spatial dim (h,w in [-1,56])
#define IMG_BYTES ((size_t)PADD * PADD * NCH)  // 430592
#define ACT_BYTES ((size_t)NB * IMG_BYTES)     // 13,778,944
#define NTILE 25                             // 128-pixel tiles per image (last half)
#define NSLOT (NB * NTILE)                   // 800 stat slots per channel

typedef int v4i __attribute__((ext_vector_type(4)));
typedef int v16i __attribute__((ext_vector_type(16)));

// ---------------------------------------------------------------------------
// 32-lane-half sum via DPP (VALU pipe). lane31 = sum(0..31), lane63 = sum(32..63).
// ---------------------------------------------------------------------------
__device__ __forceinline__ int sum32(int v) {
    v += __builtin_amdgcn_update_dpp(0, v, 0x111, 0xF, 0xF, true);  // row_shr:1
    v += __builtin_amdgcn_update_dpp(0, v, 0x112, 0xF, 0xF, true);  // row_shr:2
    v += __builtin_amdgcn_update_dpp(0, v, 0x114, 0xF, 0xF, true);  // row_shr:4
    v += __builtin_amdgcn_update_dpp(0, v, 0x118, 0xF, 0xF, true);  // row_shr:8
    v += __builtin_amdgcn_update_dpp(0, v, 0x142, 0xF, 0xF, true);  // row_bcast:15
    return v;
}

// ---------------------------------------------------------------------------
// K1: x (NCHW f32) -> act8 (padded NHWC i8 sign, +1/-1; border stays 0 from
// the per-call memset; i8 zero contributes 0 MACs = exact zero-padding).
// ---------------------------------------------------------------------------
__global__ __launch_bounds__(256) void pack_act8(const float* __restrict__ x,
                                                 const float* __restrict__ bias0,
                                                 char* __restrict__ act8) {
    int p = blockIdx.x * 256 + threadIdx.x;
    if (p >= NPIX) return;
    int n = p / NHW_;
    int rem = p - n * NHW_;
    int h = rem / NW, wc = rem - (rem / NW) * NW;
    const float* xb = x + (size_t)n * NCH * NHW_ + rem;
    char* dst = act8 + (size_t)n * IMG_BYTES + ((size_t)(h + 1) * PADD + (wc + 1)) * NCH;
#pragma unroll
    for (int g = 0; g < 8; ++g) {
        int d[4];
#pragma unroll
        for (int dw = 0; dw < 4; ++dw) {
            unsigned v = 0;
#pragma unroll
            for (int b = 0; b < 4; ++b) {
                int c = g * 16 + dw * 4 + b;
                bool pos = (xb[(size_t)c * NHW_] + bias0[c]) > 0.f;
                v |= (unsigned)(pos ? 0x01u : 0xFFu) << (8 * b);
            }
            d[dw] = (int)v;
        }
        v4i q = {d[0], d[1], d[2], d[3]};
        *reinterpret_cast<v4i*>(dst + g * 16) = q;
    }
}

// ---------------------------------------------------------------------------
// K2: weights -> w8[tap][o][c] i8 sign + scaleW[o] = mean|w|.
// ---------------------------------------------------------------------------
__global__ __launch_bounds__(128) void pack_wgt8(const float* __restrict__ w,
                                                 char* __restrict__ w8,
                                                 float* __restrict__ scaleW) {
    __shared__ float red[128];
    int o = blockIdx.x, c = threadIdx.x;  // 128 threads = ch_in
    const float* wo = w + ((size_t)o * NCH + c) * 9;
    float s = 0.f;
#pragma unroll
    for (int t = 0; t < 9; ++t) {
        float v = wo[t];
        s += fabsf(v);
        w8[(size_t)t * NCH * NCH + (size_t)o * NCH + c] = (v > 0.f) ? 1 : -1;
    }
    red[c] = s;
    __syncthreads();
    for (int st = 64; st; st >>= 1) {
        if (c < st) red[c] += red[c + st];
        __syncthreads();
    }
    if (c == 0) scaleW[o] = red[0] / 1152.0f;
}

// ---------------------------------------------------------------------------
// K3: binary conv as i8 MFMA GEMM. Block = 256 threads (4 waves); block covers
// (n, 128-pixel tile); wave wv = 32-ch_out group. 9 taps x 4 ksteps = 36
// v_mfma_i32_32x32x32_i8 per 32x32 D-tile, 4 pixel-subtiles per wave.
// Act halo (6 padded rows x 58 cols x 128ch) staged in LDS with granule-XOR
// swizzle (consecutive pixels are 128B apart -> 32-way conflict unswizzled).
// Accumulators in AGPRs (non-rematerializable). Zero-padding exact via i8 0.
// MODE 0: per-channel partial sum/sumsq. MODE 1: fused BN+residual+PReLU out.
// ---------------------------------------------------------------------------
template <int MODE>
__global__ __launch_bounds__(256) void conv_mfma(
    const char* __restrict__ act8, const char* __restrict__ w8,
    int* __restrict__ sumP, int* __restrict__ sqP,
    const float* __restrict__ coefA, const float* __restrict__ coefB,
    const float* __restrict__ alpha, const float* __restrict__ bias2,
    const float* __restrict__ x, float* __restrict__ out) {
    __shared__ char lds[6 * PADD * NCH];  // 44544 B

    int bid = blockIdx.x;
    int n = bid / NTILE, bt = bid - n * NTILE;
    int pbase = bt * 128;
    int h0 = pbase / NW;
    bool v23 = (pbase + 64) < NHW_;  // tiles 2,3 valid (uniform; only bt=24 false)

    // Stage 6 padded rows (h0..h0+5, clamped) with granule swizzle g^=col&7.
    const char* an = act8 + (size_t)n * IMG_BYTES;
    for (int r = 0; r < 6; ++r) {
        int rp = h0 + r;
        if (rp > 57) rp = 57;
        const char* src = an + (size_t)rp * PADD * NCH;
        char* drow = lds + (size_t)r * PADD * NCH;
        for (int j = threadIdx.x; j < PADD * 8; j += 256) {
            int col = j >> 3, g = j & 7;
            v4i v = *reinterpret_cast<const v4i*>(src + col * NCH + g * 16);
            *reinterpret_cast<v4i*>(drow + col * NCH + ((g ^ (col & 7)) << 4)) = v;
        }
    }
    __syncthreads();

    int wv = threadIdx.x >> 6, lane = threadIdx.x & 63;
    int l31 = lane & 31, hl = lane >> 5;
    int og = wv;

    // Per-lane pixel coords for the 4 sub-tiles (32 consecutive pixels each).
    int p0 = pbase + l31;
    int ph0 = p0 / NW, pw0 = p0 - ph0 * NW;
    int p1 = p0 + 32, ph1 = p1 / NW, pw1 = p1 - ph1 * NW;
    int p2 = p0 + 64, ph2 = p2 / NW, pw2 = p2 - ph2 * NW;
    int p3 = p0 + 96, ph3 = p3 / NW, pw3 = p3 - ph3 * NW;
    int rb0 = (ph0 - h0) * (PADD * NCH);
    int rb1 = (ph1 - h0) * (PADD * NCH);
    int rb2 = (ph2 - h0) * (PADD * NCH);
    int rb3 = (ph3 - h0) * (PADD * NCH);

    // A-operand (weights) per-lane base: row = ch_out, k-chunk = hl*16.
    const char* wlane = w8 + ((size_t)(og * 32 + l31)) * NCH + hl * 16;

    v16i acc0 = {0}, acc1 = {0}, acc2 = {0}, acc3 = {0};

#pragma unroll
    for (int tap = 0; tap < 9; ++tap) {
        const int th = tap / 3, tw = tap - 3 * (tap / 3);
#pragma unroll
        for (int ks = 0; ks < 4; ++ks) {
            v4i a = *reinterpret_cast<const v4i*>(wlane + tap * (NCH * NCH) + ks * 32);
            int gq = ks * 2 + hl;
            {
                int col = pw0 + tw;
                int off = rb0 + th * (PADD * NCH) + col * NCH + ((gq ^ (col & 7)) << 4);
                v4i b = *reinterpret_cast<const v4i*>(lds + off);
                acc0 = __builtin_amdgcn_mfma_i32_32x32x32_i8(a, b, acc0, 0, 0, 0);
            }
            {
                int col = pw1 + tw;
                int off = rb1 + th * (PADD * NCH) + col * NCH + ((gq ^ (col & 7)) << 4);
                v4i b = *reinterpret_cast<const v4i*>(lds + off);
                acc1 = __builtin_amdgcn_mfma_i32_32x32x32_i8(a, b, acc1, 0, 0, 0);
            }
            if (v23) {
                {
                    int col = pw2 + tw;
                    int off = rb2 + th * (PADD * NCH) + col * NCH + ((gq ^ (col & 7)) << 4);
                    v4i b = *reinterpret_cast<const v4i*>(lds + off);
                    acc2 = __builtin_amdgcn_mfma_i32_32x32x32_i8(a, b, acc2, 0, 0, 0);
                }
                {
                    int col = pw3 + tw;
                    int off = rb3 + th * (PADD * NCH) + col * NCH + ((gq ^ (col & 7)) << 4);
                    v4i b = *reinterpret_cast<const v4i*>(lds + off);
                    acc3 = __builtin_amdgcn_mfma_i32_32x32x32_i8(a, b, acc3, 0, 0, 0);
                }
            }
        }
    }

    // D layout (verified, dtype-independent): col(pixel)=lane&31,
    // row(ch) = (reg&3) + 8*(reg>>2) + 4*(lane>>5).
    if (MODE == 0) {
        int slot = n * NTILE + bt;
#pragma unroll
        for (int r = 0; r < 16; ++r) {
            int d0 = acc0[r], d1 = acc1[r];
            int s = d0 + d1;
            int q = d0 * d0 + d1 * d1;
            if (v23) {
                int d2 = acc2[r], d3 = acc3[r];
                s += d2 + d3;
                q += d2 * d2 + d3 * d3;
            }
            s = sum32(s);
            q = sum32(q);
            if (l31 == 31) {
                int ch = og * 32 + (r & 3) + 8 * (r >> 2) + 4 * hl;
                sumP[ch * NSLOT + slot] = s;
                sqP[ch * NSLOT + slot] = q;
            }
        }
    } else {
#pragma unroll
        for (int r = 0; r < 16; ++r) {
            int ch = og * 32 + (r & 3) + 8 * (r >> 2) + 4 * hl;
            float ca = coefA[ch], cb = coefB[ch], al = alpha[ch], b2 = bias2[ch];
            size_t base = ((size_t)n * NCH + ch) * NHW_ + pbase + l31;
            float t0 = fmaf(ca, (float)acc0[r], cb) + x[base];
            t0 = t0 >= 0.f ? t0 : al * t0;
            out[base] = t0 + b2;
            float t1 = fmaf(ca, (float)acc1[r], cb) + x[base + 32];
            t1 = t1 >= 0.f ? t1 : al * t1;
            out[base + 32] = t1 + b2;
            if (v23) {
                float t2 = fmaf(ca, (float)acc2[r], cb) + x[base + 64];
                t2 = t2 >= 0.f ? t2 : al * t2;
                out[base + 64] = t2 + b2;
                float t3 = fmaf(ca, (float)acc3[r], cb) + x[base + 96];
                t3 = t3 >= 0.f ? t3 : al * t3;
                out[base + 96] = t3 + b2;
            }
        }
    }
}

// ---------------------------------------------------------------------------
// K4: fold partial stats + scale + BN + bias1 into per-channel affine.
// 128 blocks x 64 threads; each block reduces 800 partials for one channel.
// ---------------------------------------------------------------------------
__global__ __launch_bounds__(64) void bn_coef2(const int* __restrict__ sumP,
                                               const int* __restrict__ sqP,
                                               const float* __restrict__ scaleW,
                                               const float* __restrict__ gamma,
                                               const float* __restrict__ beta,
                                               const float* __restrict__ bias1,
                                               float* __restrict__ coefA,
                                               float* __restrict__ coefB) {
    int o = blockIdx.x;
    int t = threadIdx.x;
    long long s = 0, q = 0;
    for (int i = t; i < NSLOT; i += 64) {
        s += sumP[o * NSLOT + i];
        q += sqP[o * NSLOT + i];
    }
#pragma unroll
    for (int off = 32; off; off >>= 1) {
        s += __shfl_down(s, off);
        q += __shfl_down(q, off);
    }
    if (t == 0) {
        double cnt = (double)NPIX;
        double mean = (double)s / cnt;
        double var = (double)q / cnt - mean * mean;
        if (var < 0.0) var = 0.0;
        float sc = scaleW[o];
        float rs = rsqrtf((float)((double)sc * (double)sc * var) + 1e-5f);
        float g = gamma[o];
        coefA[o] = sc * g * rs;
        coefB[o] = beta[o] - (float)((double)sc * mean) * g * rs + bias1[o];
    }
}

// ---------------------------------------------------------------------------
// Workspace layout (bytes):
//   0          act8   (32*58*58*128 i8)  13,778,944
//   13778944   w8     (9*128*128 i8)        147,456
//   13926400   scaleW (128 f32)                 512
//   13926912   coefA  (128 f32)                 512
//   13927424   coefB  (128 f32)                 512
//   13927936   sumP   (128*800 i32)          409,600
//   14337536   sqP    (128*800 i32)          409,600  -> total 14,747,136
// ---------------------------------------------------------------------------
extern "C" void kernel_launch(void* const* d_in, const int* in_sizes, int n_in,
                              void* d_out, int out_size, void* d_ws, size_t ws_size,
                              hipStream_t stream) {
    (void)in_sizes; (void)n_in; (void)out_size; (void)ws_size;
    const float* x     = (const float*)d_in[0];
    const float* bias0 = (const float*)d_in[1];
    const float* w     = (const float*)d_in[2];
    const float* gamma = (const float*)d_in[3];
    const float* beta  = (const float*)d_in[4];
    const float* bias1 = (const float*)d_in[5];
    const float* alpha = (const float*)d_in[6];
    const float* bias2 = (const float*)d_in[7];
    float* out = (float*)d_out;
    char* ws = (char*)d_ws;

    char*  act8   = ws;
    char*  w8     = ws + 13778944;
    float* scaleW = (float*)(ws + 13926400);
    float* coefA  = (float*)(ws + 13926912);
    float* coefB  = (float*)(ws + 13927424);
    int*   sumP   = (int*)(ws + 13927936);
    int*   sqP    = (int*)(ws + 14337536);

    hipMemsetAsync(act8, 0, ACT_BYTES, stream);
    pack_act8<<<(NPIX + 255) / 256, 256, 0, stream>>>(x, bias0, act8);
    pack_wgt8<<<NCH, 128, 0, stream>>>(w, w8, scaleW);

    conv_mfma<0><<<NB * NTILE, 256, 0, stream>>>(
        act8, w8, sumP, sqP, nullptr, nullptr, nullptr, nullptr, nullptr, nullptr);
    bn_coef2<<<NCH, 64, 0, stream>>>(sumP, sqP, scaleW, gamma, beta, bias1, coefA, coefB);
    conv_mfma<1><<<NB * NTILE, 256, 0, stream>>>(
        act8, w8, sumP, sqP, coefA, coefB, alpha, bias2, x, out);
}